// Round 1
// baseline (192.509 us; speedup 1.0000x reference)
//
#include <hip/hip_runtime.h>

// Problem dims
#define BDIM 4
#define TDIM 2048
#define DDIM 2048
#define KLAM 4
#define CCH  32          // time chunks
#define TC   64          // TDIM / CCH
#define MROWS (BDIM*TDIM) // 8192

using short8 = __attribute__((ext_vector_type(8))) short;
using f32x4  = __attribute__((ext_vector_type(4))) float;
typedef unsigned short ushort_t;
typedef unsigned int   uint_t;

__device__ __forceinline__ uint_t f2bf(float f) {
  uint_t u = __builtin_bit_cast(uint_t, f);
  return (u + 0x7FFFu + ((u >> 16) & 1u)) >> 16;
}

// ---------------- fp32 -> bf16 convert (8 elems / thread) ----------------
__global__ __launch_bounds__(256) void cvt_bf16(const float* __restrict__ in,
                                                uint4* __restrict__ out, int n8) {
  int i = blockIdx.x * 256 + threadIdx.x;
  if (i >= n8) return;
  const float4* in4 = (const float4*)in;
  float4 f0 = in4[2 * i];
  float4 f1 = in4[2 * i + 1];
  uint4 o;
  o.x = f2bf(f0.x) | (f2bf(f0.y) << 16);
  o.y = f2bf(f0.z) | (f2bf(f0.w) << 16);
  o.z = f2bf(f1.x) | (f2bf(f1.y) << 16);
  o.w = f2bf(f1.z) | (f2bf(f1.w) << 16);
  out[i] = o;
}

// ---------------- bf16 GEMM, z = A @ B^T (m97 structure) ----------------
// A: [8192, 2048] bf16 row-major (x), Bm: [2048, 2048] bf16 row-major (W[e,d])
// C: [8192, 2048] fp32.  128x128 tile, BK=32, 4 waves (2x2), 4x4 16x16 frags.
__global__ __launch_bounds__(256) void gemm_bt(const ushort_t* __restrict__ A,
                                               const ushort_t* __restrict__ Bm,
                                               float* __restrict__ C) {
  const int N = 2048, Kd = 2048;
  __shared__ ushort_t As[128][32];
  __shared__ ushort_t Bs[128][32];

  // XCD-aware swizzle: grid = 1024 (multiple of 8)
  int bid = blockIdx.x;
  int cpx = gridDim.x >> 3;
  int swz = (bid & 7) * cpx + (bid >> 3);
  int tm = swz >> 4;          // 64 row tiles
  int tn = swz & 15;          // 16 col tiles

  int tid  = threadIdx.x;
  int lane = tid & 63;
  int w    = tid >> 6;        // wave 0..3
  int wr   = w >> 1, wc = w & 1;

  int rowBase = tm * 128;
  int colBase = tn * 128;

  f32x4 zero = {0.f, 0.f, 0.f, 0.f};
  f32x4 acc[4][4];
#pragma unroll
  for (int m = 0; m < 4; ++m)
#pragma unroll
    for (int n = 0; n < 4; ++n) acc[m][n] = zero;

  const ushort_t* gA = A + (size_t)rowBase * Kd;
  const ushort_t* gB = Bm + (size_t)colBase * Kd;

  int r0 = lane >> 2;          // row within 16-row staging group
  int kc = (lane & 3) * 8;     // k element offset (8 bf16 = 16B)
  int krow = (lane >> 4) * 8;  // fragment k offset
  int fr = lane & 15;          // fragment row/col index

  for (int kt = 0; kt < Kd; kt += 32) {
#pragma unroll
    for (int j = 0; j < 2; ++j) {
      int rbase = 16 * (w * 2 + j);
      const ushort_t* ga = gA + (size_t)(rbase + r0) * Kd + kt + kc;
      const ushort_t* gb = gB + (size_t)(rbase + r0) * Kd + kt + kc;
      __builtin_amdgcn_global_load_lds(
          (const __attribute__((address_space(1))) void*)ga,
          (__attribute__((address_space(3))) void*)&As[rbase][0], 16, 0, 0);
      __builtin_amdgcn_global_load_lds(
          (const __attribute__((address_space(1))) void*)gb,
          (__attribute__((address_space(3))) void*)&Bs[rbase][0], 16, 0, 0);
    }
    asm volatile("s_waitcnt vmcnt(0)" ::: "memory");
    __syncthreads();

    short8 a[4], b[4];
#pragma unroll
    for (int m = 0; m < 4; ++m)
      a[m] = *(const short8*)&As[wr * 64 + m * 16 + fr][krow];
#pragma unroll
    for (int n = 0; n < 4; ++n)
      b[n] = *(const short8*)&Bs[wc * 64 + n * 16 + fr][krow];
#pragma unroll
    for (int m = 0; m < 4; ++m)
#pragma unroll
      for (int n = 0; n < 4; ++n)
        acc[m][n] = __builtin_amdgcn_mfma_f32_16x16x32_bf16(a[m], b[n], acc[m][n], 0, 0, 0);
    __syncthreads();
  }

  // epilogue: C/D layout col = lane&15, row = (lane>>4)*4 + r
  int crow0 = (lane >> 4) * 4;
  int ccol  = lane & 15;
#pragma unroll
  for (int m = 0; m < 4; ++m)
#pragma unroll
    for (int n = 0; n < 4; ++n)
#pragma unroll
      for (int r = 0; r < 4; ++r) {
        int grow = rowBase + wr * 64 + m * 16 + crow0 + r;
        int gcol = colBase + wc * 64 + n * 16 + ccol;
        C[(size_t)grow * N + gcol] = acc[m][n][r];
      }
}

// ---------------- local gated scan over time chunks (in-place z -> h_partial) ----------------
// blockIdx.x = ((b*CCH + c)*8 + dg), 256 threads over d
__global__ __launch_bounds__(256) void scan_local(float* __restrict__ z,
                                                  float* __restrict__ mfin,
                                                  const float* __restrict__ lam_logit,
                                                  const float* __restrict__ eta) {
  int bid = blockIdx.x;
  int dg = bid & 7;
  int bc = bid >> 3;
  int c = bc & (CCH - 1);
  int b = bc >> 5;
  int d = dg * 256 + threadIdx.x;

  float lam[KLAM], et[KLAM];
#pragma unroll
  for (int k = 0; k < KLAM; ++k) {
    lam[k] = 1.f / (1.f + __expf(-lam_logit[k]));
    et[k] = eta[k];
  }
  float m[KLAM] = {0.f, 0.f, 0.f, 0.f};
  size_t base = ((size_t)b * TDIM + (size_t)c * TC) * DDIM + d;
#pragma unroll 4
  for (int t = 0; t < TC; ++t) {
    float zv = z[base + (size_t)t * DDIM];
    float h = zv;
#pragma unroll
    for (int k = 0; k < KLAM; ++k) {
      m[k] = fmaf(lam[k], m[k], zv);
      h = fmaf(et[k], m[k], h);
    }
    z[base + (size_t)t * DDIM] = h;
  }
#pragma unroll
  for (int k = 0; k < KLAM; ++k)
    mfin[(((size_t)(b * CCH + c)) * KLAM + k) * DDIM + d] = m[k];
}

// ---------------- carry prefix across chunks ----------------
// one thread per (b,k,d): 32768 threads
__global__ __launch_bounds__(256) void scan_carry(const float* __restrict__ mfin,
                                                  float* __restrict__ carry,
                                                  const float* __restrict__ lam_logit) {
  int idx = blockIdx.x * 256 + threadIdx.x;
  int d = idx & (DDIM - 1);
  int k = (idx >> 11) & 3;
  int b = idx >> 13;
  float lam = 1.f / (1.f + __expf(-lam_logit[k]));
  // lam^64 by repeated squaring (exact-ish)
  float lamTc = lam;
  lamTc *= lamTc; lamTc *= lamTc; lamTc *= lamTc;
  lamTc *= lamTc; lamTc *= lamTc; lamTc *= lamTc;
  float run = 0.f;
  carry[(((size_t)(b * CCH + 0)) * KLAM + k) * DDIM + d] = 0.f;
  for (int c = 1; c < CCH; ++c) {
    run = fmaf(lamTc, run, mfin[(((size_t)(b * CCH + c - 1)) * KLAM + k) * DDIM + d]);
    carry[(((size_t)(b * CCH + c)) * KLAM + k) * DDIM + d] = run;
  }
}

// ---------------- carry correction + LayerNorm (block per (b,t)) ----------------
__global__ __launch_bounds__(256) void ln_fuse(const float* __restrict__ hpart,
                                               const float* __restrict__ carry,
                                               const float* __restrict__ lam_logit,
                                               const float* __restrict__ eta,
                                               const float* __restrict__ gamma,
                                               const float* __restrict__ beta,
                                               float* __restrict__ out) {
  int bt = blockIdx.x;            // b*TDIM + t
  int t = bt & (TDIM - 1);
  int b = bt >> 11;
  int c = t >> 6;                 // chunk
  int dt = (t & (TC - 1)) + 1;

  float sc[KLAM];
#pragma unroll
  for (int k = 0; k < KLAM; ++k) {
    float lam = 1.f / (1.f + __expf(-lam_logit[k]));
    sc[k] = eta[k] * powf(lam, (float)dt);
  }

  int d0 = threadIdx.x * 8;
  size_t rowoff = (size_t)bt * DDIM;

  float h[8];
  {
    float4 h0 = *(const float4*)&hpart[rowoff + d0];
    float4 h1 = *(const float4*)&hpart[rowoff + d0 + 4];
    h[0] = h0.x; h[1] = h0.y; h[2] = h0.z; h[3] = h0.w;
    h[4] = h1.x; h[5] = h1.y; h[6] = h1.z; h[7] = h1.w;
  }
  size_t cb = ((size_t)(b * CCH + c)) * KLAM * DDIM + d0;
#pragma unroll
  for (int k = 0; k < KLAM; ++k) {
    float4 c0 = *(const float4*)&carry[cb + (size_t)k * DDIM];
    float4 c1 = *(const float4*)&carry[cb + (size_t)k * DDIM + 4];
    h[0] = fmaf(sc[k], c0.x, h[0]);
    h[1] = fmaf(sc[k], c0.y, h[1]);
    h[2] = fmaf(sc[k], c0.z, h[2]);
    h[3] = fmaf(sc[k], c0.w, h[3]);
    h[4] = fmaf(sc[k], c1.x, h[4]);
    h[5] = fmaf(sc[k], c1.y, h[5]);
    h[6] = fmaf(sc[k], c1.z, h[6]);
    h[7] = fmaf(sc[k], c1.w, h[7]);
  }

  float s = 0.f, ss = 0.f;
#pragma unroll
  for (int j = 0; j < 8; ++j) { s += h[j]; ss += h[j] * h[j]; }
#pragma unroll
  for (int off = 32; off > 0; off >>= 1) {
    s  += __shfl_xor(s, off, 64);
    ss += __shfl_xor(ss, off, 64);
  }
  __shared__ float red[8];
  int wv = threadIdx.x >> 6;
  if ((threadIdx.x & 63) == 0) { red[wv] = s; red[4 + wv] = ss; }
  __syncthreads();
  float st  = red[0] + red[1] + red[2] + red[3];
  float sst = red[4] + red[5] + red[6] + red[7];

  const float invD = 1.f / (float)DDIM;
  float mu = st * invD;
  float var = sst * invD - mu * mu;
  float inv = rsqrtf(var + 1e-5f);

  float4 g0 = *(const float4*)&gamma[d0];
  float4 g1 = *(const float4*)&gamma[d0 + 4];
  float4 b0 = *(const float4*)&beta[d0];
  float4 b1 = *(const float4*)&beta[d0 + 4];
  float4 o0, o1;
  o0.x = g0.x * (h[0] - mu) * inv + b0.x;
  o0.y = g0.y * (h[1] - mu) * inv + b0.y;
  o0.z = g0.z * (h[2] - mu) * inv + b0.z;
  o0.w = g0.w * (h[3] - mu) * inv + b0.w;
  o1.x = g1.x * (h[4] - mu) * inv + b1.x;
  o1.y = g1.y * (h[5] - mu) * inv + b1.y;
  o1.z = g1.z * (h[6] - mu) * inv + b1.z;
  o1.w = g1.w * (h[7] - mu) * inv + b1.w;
  *(float4*)&out[rowoff + d0] = o0;
  *(float4*)&out[rowoff + d0 + 4] = o1;
}

extern "C" void kernel_launch(void* const* d_in, const int* in_sizes, int n_in,
                              void* d_out, int out_size, void* d_ws, size_t ws_size,
                              hipStream_t stream) {
  const float* x         = (const float*)d_in[0];
  const float* W         = (const float*)d_in[1];
  const float* lam_logit = (const float*)d_in[2];
  const float* eta       = (const float*)d_in[3];
  const float* gamma     = (const float*)d_in[4];
  const float* beta      = (const float*)d_in[5];
  float* out = (float*)d_out;

  char* ws = (char*)d_ws;
  // layout: [xb 32MB][Wb 8MB][z 64MB]; mfin/carry (4MB each) overlay xb after GEMM
  ushort_t* xb = (ushort_t*)ws;
  ushort_t* Wb = (ushort_t*)(ws + (size_t)33554432);
  float*    z  = (float*)(ws + (size_t)33554432 + 8388608);
  float*    mfin  = (float*)ws;                       // reuses xb region (dead after GEMM)
  float*    carry = (float*)(ws + (size_t)4194304);   // still inside xb region

  const int nX8 = (BDIM * TDIM * DDIM) / 8;  // 2097152
  const int nW8 = (DDIM * DDIM) / 8;         // 524288
  cvt_bf16<<<nX8 / 256, 256, 0, stream>>>(x, (uint4*)xb, nX8);
  cvt_bf16<<<nW8 / 256, 256, 0, stream>>>(W, (uint4*)Wb, nW8);

  gemm_bt<<<1024, 256, 0, stream>>>(xb, Wb, z);

  scan_local<<<BDIM * CCH * 8, 256, 0, stream>>>(z, mfin, lam_logit, eta);
  scan_carry<<<(BDIM * KLAM * DDIM) / 256, 256, 0, stream>>>(mfin, carry, lam_logit);
  ln_fuse<<<BDIM * TDIM, 256, 0, stream>>>(z, carry, lam_logit, eta, gamma, beta, out);
}

// Round 2
// 174.776 us; speedup vs baseline: 1.1015x; 1.1015x over previous
//
#include <hip/hip_runtime.h>

// Problem dims
#define BDIM 4
#define TDIM 2048
#define DDIM 2048
#define KLAM 4
#define CCH  32          // time chunks
#define TC   64          // TDIM / CCH

using short8 = __attribute__((ext_vector_type(8))) short;
using f32x4  = __attribute__((ext_vector_type(4))) float;
typedef unsigned short ushort_t;
typedef unsigned int   uint_t;

__device__ __forceinline__ uint_t f2bf(float f) {
  uint_t u = __builtin_bit_cast(uint_t, f);
  return (u + 0x7FFFu + ((u >> 16) & 1u)) >> 16;
}

// ---------------- fp32 -> bf16 convert (8 elems / thread) ----------------
__global__ __launch_bounds__(256) void cvt_bf16(const float* __restrict__ in,
                                                uint4* __restrict__ out, int n8) {
  int i = blockIdx.x * 256 + threadIdx.x;
  if (i >= n8) return;
  const float4* in4 = (const float4*)in;
  float4 f0 = in4[2 * i];
  float4 f1 = in4[2 * i + 1];
  uint4 o;
  o.x = f2bf(f0.x) | (f2bf(f0.y) << 16);
  o.y = f2bf(f0.z) | (f2bf(f0.w) << 16);
  o.z = f2bf(f1.x) | (f2bf(f1.y) << 16);
  o.w = f2bf(f1.z) | (f2bf(f1.w) << 16);
  out[i] = o;
}

// ======================= 8-phase 256x256 bf16 GEMM ========================
// z = A @ B^T.  A:[8192,2048] bf16 rm, Bm:[2048,2048] bf16 rm, C:[8192,2048] f32.
// BM=BN=256, BK=64 (2 K-halves of 32), 8 waves (2Mx4N), 512 thr, 128KiB LDS.
// Slots: s{A,B}[buf][kh] = 256 rows x 32 cols bf16 = 16KB, XOR-swizzled
// (byte ^= ((row>>1)&3)<<4), gload_lds linear dst + inverse-swizzled src.
// Counted vmcnt(4) once per K-tile; raw s_barrier (no vmcnt(0) drain).

#define BAR() asm volatile("s_barrier" ::: "memory")

__device__ __forceinline__ void stage_slot(const char* gbase, int growbase,
                                           ushort_t* slot, int tile, int kh,
                                           int tid) {
#pragma unroll
  for (int q = 0; q < 2; ++q) {
    int o = q * 8192 + tid * 16;
    int lb = o ^ (((o >> 7) & 3) << 4);   // inverse-swizzled logical byte
    const char* src = gbase +
        ((size_t)(growbase + (lb >> 6)) * DDIM + (size_t)tile * 64 + (size_t)kh * 32) * 2
        + (lb & 63);
    __builtin_amdgcn_global_load_lds(
        (const __attribute__((address_space(1))) void*)src,
        (__attribute__((address_space(3))) void*)((char*)slot + o), 16, 0, 0);
  }
}

__global__ __launch_bounds__(512, 2) void gemm256(const ushort_t* __restrict__ A,
                                                  const ushort_t* __restrict__ Bm,
                                                  float* __restrict__ C) {
  const int N = 2048;
  const int NT = 32;  // 2048 / 64
  __shared__ alignas(16) ushort_t sA[2][2][8192];  // [buf][kh][256*32]
  __shared__ alignas(16) ushort_t sB[2][2][8192];

  // XCD swizzle: 256 blocks, each XCD owns one column panel (B panel hot in L2)
  int bid = blockIdx.x;
  int swz = (bid & 7) * 32 + (bid >> 3);
  int tn = swz >> 5;           // 8 col tiles
  int tm = swz & 31;           // 32 row tiles
  int rowBase = tm * 256;
  int colBase = tn * 256;

  int tid  = threadIdx.x;
  int lane = tid & 63;
  int wid  = tid >> 6;
  int wm = wid >> 2;           // 0..1
  int wn = wid & 3;            // 0..3
  int fr  = lane & 15;
  int c16 = lane >> 4;

  // precomputed swizzled LDS byte offsets for fragment reads
  int lbA[2][4], lbB[4];
#pragma unroll
  for (int mh = 0; mh < 2; ++mh)
#pragma unroll
    for (int m = 0; m < 4; ++m) {
      int row = wm * 128 + mh * 64 + m * 16 + fr;
      lbA[mh][m] = (row * 64 + c16 * 16) ^ (((row >> 1) & 3) << 4);
    }
#pragma unroll
  for (int n = 0; n < 4; ++n) {
    int row = wn * 64 + n * 16 + fr;
    lbB[n] = (row * 64 + c16 * 16) ^ (((row >> 1) & 3) << 4);
  }

  f32x4 acc[8][4];
#pragma unroll
  for (int m = 0; m < 8; ++m)
#pragma unroll
    for (int n = 0; n < 4; ++n) acc[m][n] = (f32x4){0.f, 0.f, 0.f, 0.f};

  const char* gA = (const char*)A;
  const char* gB = (const char*)Bm;

  // ---- prologue: tile0 kh0, tile0 kh1, tile1 kh0  (6 granules, 12 loads)
  stage_slot(gA, rowBase, &sA[0][0][0], 0, 0, tid);
  stage_slot(gB, colBase, &sB[0][0][0], 0, 0, tid);
  stage_slot(gA, rowBase, &sA[0][1][0], 0, 1, tid);
  stage_slot(gB, colBase, &sB[0][1][0], 0, 1, tid);
  stage_slot(gA, rowBase, &sA[1][0][0], 1, 0, tid);
  stage_slot(gB, colBase, &sB[1][0][0], 1, 0, tid);
  asm volatile("s_waitcnt vmcnt(4)" ::: "memory");
  BAR();

  short8 a[4], b[4];

#define LDA(buf, mh, kh)                                                      \
  {                                                                           \
    const char* base = (const char*)&sA[buf][kh][0];                          \
    a[0] = *(const short8*)(base + lbA[mh][0]);                               \
    a[1] = *(const short8*)(base + lbA[mh][1]);                               \
    a[2] = *(const short8*)(base + lbA[mh][2]);                               \
    a[3] = *(const short8*)(base + lbA[mh][3]);                               \
  }
#define LDB(buf, kh)                                                          \
  {                                                                           \
    const char* base = (const char*)&sB[buf][kh][0];                          \
    b[0] = *(const short8*)(base + lbB[0]);                                   \
    b[1] = *(const short8*)(base + lbB[1]);                                   \
    b[2] = *(const short8*)(base + lbB[2]);                                   \
    b[3] = *(const short8*)(base + lbB[3]);                                   \
  }
#define MFMA16(mbase)                                                         \
  __builtin_amdgcn_s_setprio(1);                                              \
  _Pragma("unroll") for (int n = 0; n < 4; ++n) {                             \
    _Pragma("unroll") for (int m = 0; m < 4; ++m) {                           \
      acc[(mbase) + m][n] = __builtin_amdgcn_mfma_f32_16x16x32_bf16(          \
          a[m], b[n], acc[(mbase) + m][n], 0, 0, 0);                          \
    }                                                                         \
  }                                                                           \
  __builtin_amdgcn_s_setprio(0);

  for (int kt = 0; kt < NT; ++kt) {
    int buf = kt & 1;
    // ---- ph1: (mh0, kh0); stage A:kh1(kt+1) -> buf^1
    LDA(buf, 0, 0);
    LDB(buf, 0);
    if (kt + 1 < NT) stage_slot(gA, rowBase, &sA[buf ^ 1][1][0], kt + 1, 1, tid);
    BAR();
    MFMA16(0);
    BAR();
    // ---- ph2: (mh1, kh0); stage B:kh1(kt+1) -> buf^1
    LDA(buf, 1, 0);
    if (kt + 1 < NT) stage_slot(gB, colBase, &sB[buf ^ 1][1][0], kt + 1, 1, tid);
    BAR();
    MFMA16(4);
    BAR();
    // ---- ph3: (mh0, kh1); stage A:kh0(kt+2) -> buf
    LDA(buf, 0, 1);
    LDB(buf, 1);
    if (kt + 2 < NT) stage_slot(gA, rowBase, &sA[buf][0][0], kt + 2, 0, tid);
    BAR();
    MFMA16(0);
    BAR();
    // ---- ph4: (mh1, kh1); stage B:kh0(kt+2) -> buf; counted vmcnt
    LDA(buf, 1, 1);
    if (kt + 2 < NT) stage_slot(gB, colBase, &sB[buf][0][0], kt + 2, 0, tid);
    BAR();
    MFMA16(4);
    asm volatile("s_waitcnt vmcnt(4)" ::: "memory");
    BAR();
  }

  // epilogue: C/D layout col = lane&15, row = (lane>>4)*4 + r
  int crow0 = (lane >> 4) * 4;
  int ccol  = lane & 15;
#pragma unroll
  for (int mi = 0; mi < 8; ++mi)
#pragma unroll
    for (int n = 0; n < 4; ++n)
#pragma unroll
      for (int r = 0; r < 4; ++r) {
        int grow = rowBase + wm * 128 + mi * 16 + crow0 + r;
        int gcol = colBase + wn * 64 + n * 16 + ccol;
        C[(size_t)grow * N + gcol] = acc[mi][n][r];
      }
}

// ---------------- local gated scan over time chunks (in-place z -> h_partial) ----------------
__global__ __launch_bounds__(256) void scan_local(float* __restrict__ z,
                                                  float* __restrict__ mfin,
                                                  const float* __restrict__ lam_logit,
                                                  const float* __restrict__ eta) {
  int bid = blockIdx.x;
  int dg = bid & 7;
  int bc = bid >> 3;
  int c = bc & (CCH - 1);
  int b = bc >> 5;
  int d = dg * 256 + threadIdx.x;

  float lam[KLAM], et[KLAM];
#pragma unroll
  for (int k = 0; k < KLAM; ++k) {
    lam[k] = 1.f / (1.f + __expf(-lam_logit[k]));
    et[k] = eta[k];
  }
  float m[KLAM] = {0.f, 0.f, 0.f, 0.f};
  size_t base = ((size_t)b * TDIM + (size_t)c * TC) * DDIM + d;
#pragma unroll 4
  for (int t = 0; t < TC; ++t) {
    float zv = z[base + (size_t)t * DDIM];
    float h = zv;
#pragma unroll
    for (int k = 0; k < KLAM; ++k) {
      m[k] = fmaf(lam[k], m[k], zv);
      h = fmaf(et[k], m[k], h);
    }
    z[base + (size_t)t * DDIM] = h;
  }
#pragma unroll
  for (int k = 0; k < KLAM; ++k)
    mfin[(((size_t)(b * CCH + c)) * KLAM + k) * DDIM + d] = m[k];
}

// ---------------- carry prefix across chunks ----------------
__global__ __launch_bounds__(256) void scan_carry(const float* __restrict__ mfin,
                                                  float* __restrict__ carry,
                                                  const float* __restrict__ lam_logit) {
  int idx = blockIdx.x * 256 + threadIdx.x;
  int d = idx & (DDIM - 1);
  int k = (idx >> 11) & 3;
  int b = idx >> 13;
  float lam = 1.f / (1.f + __expf(-lam_logit[k]));
  float lamTc = lam;
  lamTc *= lamTc; lamTc *= lamTc; lamTc *= lamTc;
  lamTc *= lamTc; lamTc *= lamTc; lamTc *= lamTc;
  float run = 0.f;
  carry[(((size_t)(b * CCH + 0)) * KLAM + k) * DDIM + d] = 0.f;
  for (int c = 1; c < CCH; ++c) {
    run = fmaf(lamTc, run, mfin[(((size_t)(b * CCH + c - 1)) * KLAM + k) * DDIM + d]);
    carry[(((size_t)(b * CCH + c)) * KLAM + k) * DDIM + d] = run;
  }
}

// ---------------- carry correction + LayerNorm (block per (b,t)) ----------------
__global__ __launch_bounds__(256) void ln_fuse(const float* __restrict__ hpart,
                                               const float* __restrict__ carry,
                                               const float* __restrict__ lam_logit,
                                               const float* __restrict__ eta,
                                               const float* __restrict__ gamma,
                                               const float* __restrict__ beta,
                                               float* __restrict__ out) {
  int bt = blockIdx.x;            // b*TDIM + t
  int t = bt & (TDIM - 1);
  int b = bt >> 11;
  int c = t >> 6;                 // chunk
  int dt = (t & (TC - 1)) + 1;

  float sc[KLAM];
#pragma unroll
  for (int k = 0; k < KLAM; ++k) {
    float lam = 1.f / (1.f + __expf(-lam_logit[k]));
    sc[k] = eta[k] * powf(lam, (float)dt);
  }

  int d0 = threadIdx.x * 8;
  size_t rowoff = (size_t)bt * DDIM;

  float h[8];
  {
    float4 h0 = *(const float4*)&hpart[rowoff + d0];
    float4 h1 = *(const float4*)&hpart[rowoff + d0 + 4];
    h[0] = h0.x; h[1] = h0.y; h[2] = h0.z; h[3] = h0.w;
    h[4] = h1.x; h[5] = h1.y; h[6] = h1.z; h[7] = h1.w;
  }
  size_t cb = ((size_t)(b * CCH + c)) * KLAM * DDIM + d0;
#pragma unroll
  for (int k = 0; k < KLAM; ++k) {
    float4 c0 = *(const float4*)&carry[cb + (size_t)k * DDIM];
    float4 c1 = *(const float4*)&carry[cb + (size_t)k * DDIM + 4];
    h[0] = fmaf(sc[k], c0.x, h[0]);
    h[1] = fmaf(sc[k], c0.y, h[1]);
    h[2] = fmaf(sc[k], c0.z, h[2]);
    h[3] = fmaf(sc[k], c0.w, h[3]);
    h[4] = fmaf(sc[k], c1.x, h[4]);
    h[5] = fmaf(sc[k], c1.y, h[5]);
    h[6] = fmaf(sc[k], c1.z, h[6]);
    h[7] = fmaf(sc[k], c1.w, h[7]);
  }

  float s = 0.f, ss = 0.f;
#pragma unroll
  for (int j = 0; j < 8; ++j) { s += h[j]; ss += h[j] * h[j]; }
#pragma unroll
  for (int off = 32; off > 0; off >>= 1) {
    s  += __shfl_xor(s, off, 64);
    ss += __shfl_xor(ss, off, 64);
  }
  __shared__ float red[8];
  int wv = threadIdx.x >> 6;
  if ((threadIdx.x & 63) == 0) { red[wv] = s; red[4 + wv] = ss; }
  __syncthreads();
  float st  = red[0] + red[1] + red[2] + red[3];
  float sst = red[4] + red[5] + red[6] + red[7];

  const float invD = 1.f / (float)DDIM;
  float mu = st * invD;
  float var = sst * invD - mu * mu;
  float inv = rsqrtf(var + 1e-5f);

  float4 g0 = *(const float4*)&gamma[d0];
  float4 g1 = *(const float4*)&gamma[d0 + 4];
  float4 b0 = *(const float4*)&beta[d0];
  float4 b1 = *(const float4*)&beta[d0 + 4];
  float4 o0, o1;
  o0.x = g0.x * (h[0] - mu) * inv + b0.x;
  o0.y = g0.y * (h[1] - mu) * inv + b0.y;
  o0.z = g0.z * (h[2] - mu) * inv + b0.z;
  o0.w = g0.w * (h[3] - mu) * inv + b0.w;
  o1.x = g1.x * (h[4] - mu) * inv + b1.x;
  o1.y = g1.y * (h[5] - mu) * inv + b1.y;
  o1.z = g1.z * (h[6] - mu) * inv + b1.z;
  o1.w = g1.w * (h[7] - mu) * inv + b1.w;
  *(float4*)&out[rowoff + d0] = o0;
  *(float4*)&out[rowoff + d0 + 4] = o1;
}

extern "C" void kernel_launch(void* const* d_in, const int* in_sizes, int n_in,
                              void* d_out, int out_size, void* d_ws, size_t ws_size,
                              hipStream_t stream) {
  const float* x         = (const float*)d_in[0];
  const float* W         = (const float*)d_in[1];
  const float* lam_logit = (const float*)d_in[2];
  const float* eta       = (const float*)d_in[3];
  const float* gamma     = (const float*)d_in[4];
  const float* beta      = (const float*)d_in[5];
  float* out = (float*)d_out;

  char* ws = (char*)d_ws;
  // layout: [xb 32MB][Wb 8MB][z 64MB]; mfin/carry (4MB each) overlay xb after GEMM
  ushort_t* xb = (ushort_t*)ws;
  ushort_t* Wb = (ushort_t*)(ws + (size_t)33554432);
  float*    z  = (float*)(ws + (size_t)33554432 + 8388608);
  float*    mfin  = (float*)ws;                       // reuses xb region (dead after GEMM)
  float*    carry = (float*)(ws + (size_t)4194304);   // still inside xb region

  const int nX8 = (BDIM * TDIM * DDIM) / 8;  // 2097152
  const int nW8 = (DDIM * DDIM) / 8;         // 524288
  cvt_bf16<<<nX8 / 256, 256, 0, stream>>>(x, (uint4*)xb, nX8);
  cvt_bf16<<<nW8 / 256, 256, 0, stream>>>(W, (uint4*)Wb, nW8);

  gemm256<<<256, 512, 0, stream>>>(xb, Wb, z);

  scan_local<<<BDIM * CCH * 8, 256, 0, stream>>>(z, mfin, lam_logit, eta);
  scan_carry<<<(BDIM * KLAM * DDIM) / 256, 256, 0, stream>>>(mfin, carry, lam_logit);
  ln_fuse<<<BDIM * TDIM, 256, 0, stream>>>(z, carry, lam_logit, eta, gamma, beta, out);
}

// Round 3
// 151.673 us; speedup vs baseline: 1.2692x; 1.1523x over previous
//
#include <hip/hip_runtime.h>

// Problem dims
#define BDIM 4
#define TDIM 2048
#define DDIM 2048
#define KLAM 4
#define CCH  32          // time chunks
#define TC   64          // TDIM / CCH

using short8 = __attribute__((ext_vector_type(8))) short;
using f32x4  = __attribute__((ext_vector_type(4))) float;
typedef unsigned short ushort_t;
typedef unsigned int   uint_t;

__device__ __forceinline__ uint_t f2bf(float f) {
  uint_t u = __builtin_bit_cast(uint_t, f);
  return (u + 0x7FFFu + ((u >> 16) & 1u)) >> 16;
}
__device__ __forceinline__ float bf2f(uint_t s) {
  uint_t u = s << 16;
  return __builtin_bit_cast(float, u);
}

// ---------------- fp32 -> bf16 convert (8 elems / thread) ----------------
__global__ __launch_bounds__(256) void cvt_bf16(const float* __restrict__ in,
                                                uint4* __restrict__ out, int n8) {
  int i = blockIdx.x * 256 + threadIdx.x;
  if (i >= n8) return;
  const float4* in4 = (const float4*)in;
  float4 f0 = in4[2 * i];
  float4 f1 = in4[2 * i + 1];
  uint4 o;
  o.x = f2bf(f0.x) | (f2bf(f0.y) << 16);
  o.y = f2bf(f0.z) | (f2bf(f0.w) << 16);
  o.z = f2bf(f1.x) | (f2bf(f1.y) << 16);
  o.w = f2bf(f1.z) | (f2bf(f1.w) << 16);
  out[i] = o;
}

// ======================= 8-phase 256x256 bf16 GEMM ========================
// z = A @ B^T.  A:[8192,2048] bf16 rm, Bm:[2048,2048] bf16 rm, C(z):[8192,2048] bf16.
// BM=BN=256, BK=64 (2 K-halves of 32), 8 waves (2Mx4N), 512 thr, 128KiB LDS.
// tm-chunked XCD swizzle: XCD x owns tm in [4x,4x+4) x all 8 tn -> A fetched
// once machine-wide (L2 8-way reuse), B 8x (L3-resident).

#define BAR() asm volatile("s_barrier" ::: "memory")

__device__ __forceinline__ void stage_slot(const char* gbase, int growbase,
                                           ushort_t* slot, int tile, int kh,
                                           int tid) {
#pragma unroll
  for (int q = 0; q < 2; ++q) {
    int o = q * 8192 + tid * 16;
    int lb = o ^ (((o >> 7) & 3) << 4);   // inverse-swizzled logical byte
    const char* src = gbase +
        ((size_t)(growbase + (lb >> 6)) * DDIM + (size_t)tile * 64 + (size_t)kh * 32) * 2
        + (lb & 63);
    __builtin_amdgcn_global_load_lds(
        (const __attribute__((address_space(1))) void*)src,
        (__attribute__((address_space(3))) void*)((char*)slot + o), 16, 0, 0);
  }
}

__global__ __launch_bounds__(512, 2) void gemm256(const ushort_t* __restrict__ A,
                                                  const ushort_t* __restrict__ Bm,
                                                  ushort_t* __restrict__ Cz) {
  const int N = 2048;
  const int NT = 32;  // 2048 / 64
  __shared__ alignas(16) ushort_t sA[2][2][8192];  // [buf][kh][256*32]
  __shared__ alignas(16) ushort_t sB[2][2][8192];

  // tm-chunked XCD swizzle (bijective over 256 blocks)
  int bid = blockIdx.x;
  int tm = (bid & 7) * 4 + ((bid >> 3) >> 3);   // 32 row tiles
  int tn = (bid >> 3) & 7;                       // 8 col tiles
  int rowBase = tm * 256;
  int colBase = tn * 256;

  int tid  = threadIdx.x;
  int lane = tid & 63;
  int wid  = tid >> 6;
  int wm = wid >> 2;           // 0..1
  int wn = wid & 3;            // 0..3
  int fr  = lane & 15;
  int c16 = lane >> 4;

  // precomputed swizzled LDS byte offsets for fragment reads
  int lbA[2][4], lbB[4];
#pragma unroll
  for (int mh = 0; mh < 2; ++mh)
#pragma unroll
    for (int m = 0; m < 4; ++m) {
      int row = wm * 128 + mh * 64 + m * 16 + fr;
      lbA[mh][m] = (row * 64 + c16 * 16) ^ (((row >> 1) & 3) << 4);
    }
#pragma unroll
  for (int n = 0; n < 4; ++n) {
    int row = wn * 64 + n * 16 + fr;
    lbB[n] = (row * 64 + c16 * 16) ^ (((row >> 1) & 3) << 4);
  }

  f32x4 acc[8][4];
#pragma unroll
  for (int m = 0; m < 8; ++m)
#pragma unroll
    for (int n = 0; n < 4; ++n) acc[m][n] = (f32x4){0.f, 0.f, 0.f, 0.f};

  const char* gA = (const char*)A;
  const char* gB = (const char*)Bm;

  // ---- prologue: tile0 kh0, tile0 kh1, tile1 kh0  (6 granules, 12 loads)
  stage_slot(gA, rowBase, &sA[0][0][0], 0, 0, tid);
  stage_slot(gB, colBase, &sB[0][0][0], 0, 0, tid);
  stage_slot(gA, rowBase, &sA[0][1][0], 0, 1, tid);
  stage_slot(gB, colBase, &sB[0][1][0], 0, 1, tid);
  stage_slot(gA, rowBase, &sA[1][0][0], 1, 0, tid);
  stage_slot(gB, colBase, &sB[1][0][0], 1, 0, tid);
  asm volatile("s_waitcnt vmcnt(4)" ::: "memory");
  BAR();

  short8 a[4], b[4];

#define LDA(buf, mh, kh)                                                      \
  {                                                                           \
    const char* base = (const char*)&sA[buf][kh][0];                          \
    a[0] = *(const short8*)(base + lbA[mh][0]);                               \
    a[1] = *(const short8*)(base + lbA[mh][1]);                               \
    a[2] = *(const short8*)(base + lbA[mh][2]);                               \
    a[3] = *(const short8*)(base + lbA[mh][3]);                               \
  }
#define LDB(buf, kh)                                                          \
  {                                                                           \
    const char* base = (const char*)&sB[buf][kh][0];                          \
    b[0] = *(const short8*)(base + lbB[0]);                                   \
    b[1] = *(const short8*)(base + lbB[1]);                                   \
    b[2] = *(const short8*)(base + lbB[2]);                                   \
    b[3] = *(const short8*)(base + lbB[3]);                                   \
  }
#define MFMA16(mbase)                                                         \
  __builtin_amdgcn_s_setprio(1);                                              \
  _Pragma("unroll") for (int n = 0; n < 4; ++n) {                             \
    _Pragma("unroll") for (int m = 0; m < 4; ++m) {                           \
      acc[(mbase) + m][n] = __builtin_amdgcn_mfma_f32_16x16x32_bf16(          \
          a[m], b[n], acc[(mbase) + m][n], 0, 0, 0);                          \
    }                                                                         \
  }                                                                           \
  __builtin_amdgcn_s_setprio(0);

  for (int kt = 0; kt < NT; ++kt) {
    int buf = kt & 1;
    // ---- ph1: (mh0, kh0); stage A:kh1(kt+1) -> buf^1
    LDA(buf, 0, 0);
    LDB(buf, 0);
    if (kt + 1 < NT) stage_slot(gA, rowBase, &sA[buf ^ 1][1][0], kt + 1, 1, tid);
    BAR();
    MFMA16(0);
    BAR();
    // ---- ph2: (mh1, kh0); stage B:kh1(kt+1) -> buf^1
    LDA(buf, 1, 0);
    if (kt + 1 < NT) stage_slot(gB, colBase, &sB[buf ^ 1][1][0], kt + 1, 1, tid);
    BAR();
    MFMA16(4);
    BAR();
    // ---- ph3: (mh0, kh1); stage A:kh0(kt+2) -> buf
    LDA(buf, 0, 1);
    LDB(buf, 1);
    if (kt + 2 < NT) stage_slot(gA, rowBase, &sA[buf][0][0], kt + 2, 0, tid);
    BAR();
    MFMA16(0);
    BAR();
    // ---- ph4: (mh1, kh1); stage B:kh0(kt+2) -> buf; counted vmcnt
    LDA(buf, 1, 1);
    if (kt + 2 < NT) stage_slot(gB, colBase, &sB[buf][0][0], kt + 2, 0, tid);
    BAR();
    MFMA16(4);
    asm volatile("s_waitcnt vmcnt(4)" ::: "memory");
    BAR();
  }

  // epilogue: C/D layout col = lane&15, row = (lane>>4)*4 + r ; write bf16
  int crow0 = (lane >> 4) * 4;
  int ccol  = lane & 15;
#pragma unroll
  for (int mi = 0; mi < 8; ++mi)
#pragma unroll
    for (int n = 0; n < 4; ++n)
#pragma unroll
      for (int r = 0; r < 4; ++r) {
        int grow = rowBase + wm * 128 + mi * 16 + crow0 + r;
        int gcol = colBase + wn * 64 + n * 16 + ccol;
        Cz[(size_t)grow * N + gcol] = (ushort_t)f2bf(acc[mi][n][r]);
      }
}

// ---------------- local gated scan over time chunks (bf16 z -> bf16 h, in place) ----------------
// blockIdx.x = ((b*CCH + c)*4 + dg), 256 threads, 2 d per thread
__global__ __launch_bounds__(256) void scan_local(ushort_t* __restrict__ z,
                                                  float* __restrict__ mfin,
                                                  const float* __restrict__ lam_logit,
                                                  const float* __restrict__ eta) {
  int bid = blockIdx.x;
  int dg = bid & 3;
  int bc = bid >> 2;
  int c = bc & (CCH - 1);
  int b = bc >> 5;
  int d0 = dg * 512 + threadIdx.x * 2;

  float lam[KLAM], et[KLAM];
#pragma unroll
  for (int k = 0; k < KLAM; ++k) {
    lam[k] = 1.f / (1.f + __expf(-lam_logit[k]));
    et[k] = eta[k];
  }
  float m0[KLAM] = {0.f, 0.f, 0.f, 0.f};
  float m1[KLAM] = {0.f, 0.f, 0.f, 0.f};
  size_t base = ((size_t)b * TDIM + (size_t)c * TC) * DDIM + d0;
#pragma unroll 4
  for (int t = 0; t < TC; ++t) {
    uint_t v = *(const uint_t*)&z[base + (size_t)t * DDIM];
    float z0 = bf2f(v & 0xffffu);
    float z1 = bf2f(v >> 16);
    float h0 = z0, h1 = z1;
#pragma unroll
    for (int k = 0; k < KLAM; ++k) {
      m0[k] = fmaf(lam[k], m0[k], z0);
      m1[k] = fmaf(lam[k], m1[k], z1);
      h0 = fmaf(et[k], m0[k], h0);
      h1 = fmaf(et[k], m1[k], h1);
    }
    *(uint_t*)&z[base + (size_t)t * DDIM] = f2bf(h0) | (f2bf(h1) << 16);
  }
#pragma unroll
  for (int k = 0; k < KLAM; ++k) {
    float2 mm = {m0[k], m1[k]};
    *(float2*)&mfin[(((size_t)(b * CCH + c)) * KLAM + k) * DDIM + d0] = mm;
  }
}

// ---------------- carry prefix across chunks ----------------
__global__ __launch_bounds__(256) void scan_carry(const float* __restrict__ mfin,
                                                  float* __restrict__ carry,
                                                  const float* __restrict__ lam_logit) {
  int idx = blockIdx.x * 256 + threadIdx.x;
  int d = idx & (DDIM - 1);
  int k = (idx >> 11) & 3;
  int b = idx >> 13;
  float lam = 1.f / (1.f + __expf(-lam_logit[k]));
  float lamTc = lam;
  lamTc *= lamTc; lamTc *= lamTc; lamTc *= lamTc;
  lamTc *= lamTc; lamTc *= lamTc; lamTc *= lamTc;
  float run = 0.f;
  carry[(((size_t)(b * CCH + 0)) * KLAM + k) * DDIM + d] = 0.f;
  for (int c = 1; c < CCH; ++c) {
    run = fmaf(lamTc, run, mfin[(((size_t)(b * CCH + c - 1)) * KLAM + k) * DDIM + d]);
    carry[(((size_t)(b * CCH + c)) * KLAM + k) * DDIM + d] = run;
  }
}

// ---------------- carry correction + LayerNorm (block per (b,t)) ----------------
__global__ __launch_bounds__(256) void ln_fuse(const ushort_t* __restrict__ hpart,
                                               const float* __restrict__ carry,
                                               const float* __restrict__ lam_logit,
                                               const float* __restrict__ eta,
                                               const float* __restrict__ gamma,
                                               const float* __restrict__ beta,
                                               float* __restrict__ out) {
  int bt = blockIdx.x;            // b*TDIM + t
  int t = bt & (TDIM - 1);
  int b = bt >> 11;
  int c = t >> 6;                 // chunk
  int dt = (t & (TC - 1)) + 1;

  float sc[KLAM];
#pragma unroll
  for (int k = 0; k < KLAM; ++k) {
    float lam = 1.f / (1.f + __expf(-lam_logit[k]));
    sc[k] = eta[k] * powf(lam, (float)dt);
  }

  int d0 = threadIdx.x * 8;
  size_t rowoff = (size_t)bt * DDIM;

  float h[8];
  {
    uint4 hv = *(const uint4*)&hpart[rowoff + d0];
    h[0] = bf2f(hv.x & 0xffffu); h[1] = bf2f(hv.x >> 16);
    h[2] = bf2f(hv.y & 0xffffu); h[3] = bf2f(hv.y >> 16);
    h[4] = bf2f(hv.z & 0xffffu); h[5] = bf2f(hv.z >> 16);
    h[6] = bf2f(hv.w & 0xffffu); h[7] = bf2f(hv.w >> 16);
  }
  size_t cb = ((size_t)(b * CCH + c)) * KLAM * DDIM + d0;
#pragma unroll
  for (int k = 0; k < KLAM; ++k) {
    float4 c0 = *(const float4*)&carry[cb + (size_t)k * DDIM];
    float4 c1 = *(const float4*)&carry[cb + (size_t)k * DDIM + 4];
    h[0] = fmaf(sc[k], c0.x, h[0]);
    h[1] = fmaf(sc[k], c0.y, h[1]);
    h[2] = fmaf(sc[k], c0.z, h[2]);
    h[3] = fmaf(sc[k], c0.w, h[3]);
    h[4] = fmaf(sc[k], c1.x, h[4]);
    h[5] = fmaf(sc[k], c1.y, h[5]);
    h[6] = fmaf(sc[k], c1.z, h[6]);
    h[7] = fmaf(sc[k], c1.w, h[7]);
  }

  float s = 0.f, ss = 0.f;
#pragma unroll
  for (int j = 0; j < 8; ++j) { s += h[j]; ss += h[j] * h[j]; }
#pragma unroll
  for (int off = 32; off > 0; off >>= 1) {
    s  += __shfl_xor(s, off, 64);
    ss += __shfl_xor(ss, off, 64);
  }
  __shared__ float red[8];
  int wv = threadIdx.x >> 6;
  if ((threadIdx.x & 63) == 0) { red[wv] = s; red[4 + wv] = ss; }
  __syncthreads();
  float st  = red[0] + red[1] + red[2] + red[3];
  float sst = red[4] + red[5] + red[6] + red[7];

  const float invD = 1.f / (float)DDIM;
  float mu = st * invD;
  float var = sst * invD - mu * mu;
  float inv = rsqrtf(var + 1e-5f);

  float4 g0 = *(const float4*)&gamma[d0];
  float4 g1 = *(const float4*)&gamma[d0 + 4];
  float4 b0 = *(const float4*)&beta[d0];
  float4 b1 = *(const float4*)&beta[d0 + 4];
  float4 o0, o1;
  o0.x = g0.x * (h[0] - mu) * inv + b0.x;
  o0.y = g0.y * (h[1] - mu) * inv + b0.y;
  o0.z = g0.z * (h[2] - mu) * inv + b0.z;
  o0.w = g0.w * (h[3] - mu) * inv + b0.w;
  o1.x = g1.x * (h[4] - mu) * inv + b1.x;
  o1.y = g1.y * (h[5] - mu) * inv + b1.y;
  o1.z = g1.z * (h[6] - mu) * inv + b1.z;
  o1.w = g1.w * (h[7] - mu) * inv + b1.w;
  *(float4*)&out[rowoff + d0] = o0;
  *(float4*)&out[rowoff + d0 + 4] = o1;
}

extern "C" void kernel_launch(void* const* d_in, const int* in_sizes, int n_in,
                              void* d_out, int out_size, void* d_ws, size_t ws_size,
                              hipStream_t stream) {
  const float* x         = (const float*)d_in[0];
  const float* W         = (const float*)d_in[1];
  const float* lam_logit = (const float*)d_in[2];
  const float* eta       = (const float*)d_in[3];
  const float* gamma     = (const float*)d_in[4];
  const float* beta      = (const float*)d_in[5];
  float* out = (float*)d_out;

  char* ws = (char*)d_ws;
  // layout: [xb 32MB][Wb 8MB][zb 32MB bf16]; mfin/carry (4MB each) overlay xb after GEMM
  ushort_t* xb = (ushort_t*)ws;
  ushort_t* Wb = (ushort_t*)(ws + (size_t)33554432);
  ushort_t* zb = (ushort_t*)(ws + (size_t)33554432 + 8388608);
  float*    mfin  = (float*)ws;                       // reuses xb region (dead after GEMM)
  float*    carry = (float*)(ws + (size_t)4194304);   // still inside xb region

  const int nX8 = (BDIM * TDIM * DDIM) / 8;  // 2097152
  const int nW8 = (DDIM * DDIM) / 8;         // 524288
  cvt_bf16<<<nX8 / 256, 256, 0, stream>>>(x, (uint4*)xb, nX8);
  cvt_bf16<<<nW8 / 256, 256, 0, stream>>>(W, (uint4*)Wb, nW8);

  gemm256<<<256, 512, 0, stream>>>(xb, Wb, zb);

  scan_local<<<BDIM * CCH * 4, 256, 0, stream>>>(zb, mfin, lam_logit, eta);
  scan_carry<<<(BDIM * KLAM * DDIM) / 256, 256, 0, stream>>>(mfin, carry, lam_logit);
  ln_fuse<<<BDIM * TDIM, 256, 0, stream>>>(zb, carry, lam_logit, eta, gamma, beta, out);
}

// Round 4
// 151.536 us; speedup vs baseline: 1.2704x; 1.0009x over previous
//
#include <hip/hip_runtime.h>

// Problem dims
#define BDIM 4
#define TDIM 2048
#define DDIM 2048
#define KLAM 4
#define CCH  32          // time chunks
#define TC   64          // TDIM / CCH

using short8 = __attribute__((ext_vector_type(8))) short;
using f32x4  = __attribute__((ext_vector_type(4))) float;
typedef unsigned short ushort_t;
typedef unsigned int   uint_t;

__device__ __forceinline__ uint_t f2bf(float f) {
  uint_t u = __builtin_bit_cast(uint_t, f);
  return (u + 0x7FFFu + ((u >> 16) & 1u)) >> 16;
}
__device__ __forceinline__ float bf2f(uint_t s) {
  uint_t u = s << 16;
  return __builtin_bit_cast(float, u);
}

// ---------------- fp32 -> bf16 convert (8 elems / thread) ----------------
__global__ __launch_bounds__(256) void cvt_bf16(const float* __restrict__ in,
                                                uint4* __restrict__ out, int n8) {
  int i = blockIdx.x * 256 + threadIdx.x;
  if (i >= n8) return;
  const float4* in4 = (const float4*)in;
  float4 f0 = in4[2 * i];
  float4 f1 = in4[2 * i + 1];
  uint4 o;
  o.x = f2bf(f0.x) | (f2bf(f0.y) << 16);
  o.y = f2bf(f0.z) | (f2bf(f0.w) << 16);
  o.z = f2bf(f1.x) | (f2bf(f1.y) << 16);
  o.w = f2bf(f1.z) | (f2bf(f1.w) << 16);
  out[i] = o;
}

// ======================= 8-phase 256x256 bf16 GEMM ========================
// z = A @ B^T.  A:[8192,2048] bf16 rm, Bm:[2048,2048] bf16 rm, C(z):[8192,2048] bf16.
// BM=BN=256, BK=64 (2 K-halves of 32), 8 waves (2Mx4N), 512 thr, 128KiB LDS.
// Raw builtin s_barrier (NO memory-clobber asm barrier -> no forced vmcnt(0)
// drain); counted vmcnt(4) once per K-tile, pinned with sched_barrier(0).

#define BAR() __builtin_amdgcn_s_barrier()

// issue one granule (256 rows x 32 cols bf16 = 16KB) via 2 x gload_lds w=16
__device__ __forceinline__ void stage2(const char* b0, const char* b1,
                                       ushort_t* slot, int koff, int tid) {
  char* dst = (char*)slot + tid * 16;
  __builtin_amdgcn_global_load_lds(
      (const __attribute__((address_space(1))) void*)(b0 + koff),
      (__attribute__((address_space(3))) void*)dst, 16, 0, 0);
  __builtin_amdgcn_global_load_lds(
      (const __attribute__((address_space(1))) void*)(b1 + koff),
      (__attribute__((address_space(3))) void*)(dst + 8192), 16, 0, 0);
}

__global__ __launch_bounds__(512, 2) void gemm256(const ushort_t* __restrict__ A,
                                                  const ushort_t* __restrict__ Bm,
                                                  ushort_t* __restrict__ Cz) {
  const int N = 2048;
  const int NT = 32;  // 2048 / 64
  __shared__ alignas(16) ushort_t sA[2][2][8192];  // [buf][kh][256*32]
  __shared__ alignas(16) ushort_t sB[2][2][8192];

  // tm-chunked XCD swizzle (bijective over 256 blocks)
  int bid = blockIdx.x;
  int tm = (bid & 7) * 4 + ((bid >> 3) >> 3);   // 32 row tiles
  int tn = (bid >> 3) & 7;                       // 8 col tiles
  int rowBase = tm * 256;
  int colBase = tn * 256;

  int tid  = threadIdx.x;
  int lane = tid & 63;
  int wid  = tid >> 6;
  int wm = wid >> 2;           // 0..1
  int wn = wid & 3;            // 0..3
  int fr  = lane & 15;
  int c16 = lane >> 4;

  // per-thread swizzled global source base pointers (q=0,1 granule halves)
  const char* bA[2];
  const char* bB[2];
#pragma unroll
  for (int q = 0; q < 2; ++q) {
    int o = q * 8192 + tid * 16;
    int lb = o ^ (((o >> 7) & 3) << 4);   // inverse-swizzled logical byte
    bA[q] = (const char*)A + ((size_t)(rowBase + (lb >> 6)) * DDIM) * 2 + (lb & 63);
    bB[q] = (const char*)Bm + ((size_t)(colBase + (lb >> 6)) * DDIM) * 2 + (lb & 63);
  }
  // byte offset within a row for (tile kt, half kh) = kt*128 + kh*64

  // precomputed swizzled LDS byte offsets for fragment reads
  int lbA[2][4], lbB[4];
#pragma unroll
  for (int mh = 0; mh < 2; ++mh)
#pragma unroll
    for (int m = 0; m < 4; ++m) {
      int row = wm * 128 + mh * 64 + m * 16 + fr;
      lbA[mh][m] = (row * 64 + c16 * 16) ^ (((row >> 1) & 3) << 4);
    }
#pragma unroll
  for (int n = 0; n < 4; ++n) {
    int row = wn * 64 + n * 16 + fr;
    lbB[n] = (row * 64 + c16 * 16) ^ (((row >> 1) & 3) << 4);
  }

  f32x4 acc[8][4];
#pragma unroll
  for (int m = 0; m < 8; ++m)
#pragma unroll
    for (int n = 0; n < 4; ++n) acc[m][n] = (f32x4){0.f, 0.f, 0.f, 0.f};

  // ---- prologue: tile0 kh0, tile0 kh1, tile1 kh0  (6 granules, 12 loads)
  stage2(bA[0], bA[1], &sA[0][0][0], 0, tid);
  stage2(bB[0], bB[1], &sB[0][0][0], 0, tid);
  stage2(bA[0], bA[1], &sA[0][1][0], 64, tid);
  stage2(bB[0], bB[1], &sB[0][1][0], 64, tid);
  stage2(bA[0], bA[1], &sA[1][0][0], 128, tid);
  stage2(bB[0], bB[1], &sB[1][0][0], 128, tid);
  __builtin_amdgcn_sched_barrier(0);
  asm volatile("s_waitcnt vmcnt(4)");
  __builtin_amdgcn_sched_barrier(0);
  BAR();

  short8 a[4], b[4];

#define LDA(buf, mh, kh)                                                      \
  {                                                                           \
    const char* base = (const char*)&sA[buf][kh][0];                          \
    a[0] = *(const short8*)(base + lbA[mh][0]);                               \
    a[1] = *(const short8*)(base + lbA[mh][1]);                               \
    a[2] = *(const short8*)(base + lbA[mh][2]);                               \
    a[3] = *(const short8*)(base + lbA[mh][3]);                               \
  }
#define LDB(buf, kh)                                                          \
  {                                                                           \
    const char* base = (const char*)&sB[buf][kh][0];                          \
    b[0] = *(const short8*)(base + lbB[0]);                                   \
    b[1] = *(const short8*)(base + lbB[1]);                                   \
    b[2] = *(const short8*)(base + lbB[2]);                                   \
    b[3] = *(const short8*)(base + lbB[3]);                                   \
  }
#define MFMA16(mbase)                                                         \
  __builtin_amdgcn_s_setprio(1);                                              \
  _Pragma("unroll") for (int n = 0; n < 4; ++n) {                             \
    _Pragma("unroll") for (int m = 0; m < 4; ++m) {                           \
      acc[(mbase) + m][n] = __builtin_amdgcn_mfma_f32_16x16x32_bf16(          \
          a[m], b[n], acc[(mbase) + m][n], 0, 0, 0);                          \
    }                                                                         \
  }                                                                           \
  __builtin_amdgcn_s_setprio(0);

  for (int kt = 0; kt < NT; ++kt) {
    int buf = kt & 1;
    int k1 = (kt + 1) * 128;   // byte offsets
    int k2 = (kt + 2) * 128;
    // ---- ph1: (mh0, kh0); stage A:kh1(kt+1) -> buf^1
    LDA(buf, 0, 0);
    LDB(buf, 0);
    if (kt + 1 < NT) stage2(bA[0], bA[1], &sA[buf ^ 1][1][0], k1 + 64, tid);
    BAR();
    MFMA16(0);
    BAR();
    // ---- ph2: (mh1, kh0); stage B:kh1(kt+1) -> buf^1
    LDA(buf, 1, 0);
    if (kt + 1 < NT) stage2(bB[0], bB[1], &sB[buf ^ 1][1][0], k1 + 64, tid);
    BAR();
    MFMA16(4);
    BAR();
    // ---- ph3: (mh0, kh1); stage A:kh0(kt+2) -> buf
    LDA(buf, 0, 1);
    LDB(buf, 1);
    if (kt + 2 < NT) stage2(bA[0], bA[1], &sA[buf][0][0], k2, tid);
    BAR();
    MFMA16(0);
    BAR();
    // ---- ph4: (mh1, kh1); stage B:kh0(kt+2) -> buf; counted vmcnt
    LDA(buf, 1, 1);
    if (kt + 2 < NT) stage2(bB[0], bB[1], &sB[buf][0][0], k2, tid);
    BAR();
    MFMA16(4);
    __builtin_amdgcn_sched_barrier(0);
    asm volatile("s_waitcnt vmcnt(4)");
    __builtin_amdgcn_sched_barrier(0);
    BAR();
  }

  // epilogue: C/D layout col = lane&15, row = (lane>>4)*4 + r ; write bf16
  int crow0 = (lane >> 4) * 4;
  int ccol  = lane & 15;
#pragma unroll
  for (int mi = 0; mi < 8; ++mi)
#pragma unroll
    for (int n = 0; n < 4; ++n)
#pragma unroll
      for (int r = 0; r < 4; ++r) {
        int grow = rowBase + wm * 128 + mi * 16 + crow0 + r;
        int gcol = colBase + wn * 64 + n * 16 + ccol;
        Cz[(size_t)grow * N + gcol] = (ushort_t)f2bf(acc[mi][n][r]);
      }
}

// ---------------- local gated scan over time chunks (bf16 z -> bf16 h, in place) ----------------
// blockIdx.x = ((b*CCH + c)*4 + dg), 256 threads, 2 d per thread
__global__ __launch_bounds__(256) void scan_local(ushort_t* __restrict__ z,
                                                  float* __restrict__ mfin,
                                                  const float* __restrict__ lam_logit,
                                                  const float* __restrict__ eta) {
  int bid = blockIdx.x;
  int dg = bid & 3;
  int bc = bid >> 2;
  int c = bc & (CCH - 1);
  int b = bc >> 5;
  int d0 = dg * 512 + threadIdx.x * 2;

  float lam[KLAM], et[KLAM];
#pragma unroll
  for (int k = 0; k < KLAM; ++k) {
    lam[k] = 1.f / (1.f + __expf(-lam_logit[k]));
    et[k] = eta[k];
  }
  float m0[KLAM] = {0.f, 0.f, 0.f, 0.f};
  float m1[KLAM] = {0.f, 0.f, 0.f, 0.f};
  size_t base = ((size_t)b * TDIM + (size_t)c * TC) * DDIM + d0;
#pragma unroll 4
  for (int t = 0; t < TC; ++t) {
    uint_t v = *(const uint_t*)&z[base + (size_t)t * DDIM];
    float z0 = bf2f(v & 0xffffu);
    float z1 = bf2f(v >> 16);
    float h0 = z0, h1 = z1;
#pragma unroll
    for (int k = 0; k < KLAM; ++k) {
      m0[k] = fmaf(lam[k], m0[k], z0);
      m1[k] = fmaf(lam[k], m1[k], z1);
      h0 = fmaf(et[k], m0[k], h0);
      h1 = fmaf(et[k], m1[k], h1);
    }
    *(uint_t*)&z[base + (size_t)t * DDIM] = f2bf(h0) | (f2bf(h1) << 16);
  }
#pragma unroll
  for (int k = 0; k < KLAM; ++k) {
    float2 mm = {m0[k], m1[k]};
    *(float2*)&mfin[(((size_t)(b * CCH + c)) * KLAM + k) * DDIM + d0] = mm;
  }
}

// ---------------- carry prefix across chunks ----------------
__global__ __launch_bounds__(256) void scan_carry(const float* __restrict__ mfin,
                                                  float* __restrict__ carry,
                                                  const float* __restrict__ lam_logit) {
  int idx = blockIdx.x * 256 + threadIdx.x;
  int d = idx & (DDIM - 1);
  int k = (idx >> 11) & 3;
  int b = idx >> 13;
  float lam = 1.f / (1.f + __expf(-lam_logit[k]));
  float lamTc = lam;
  lamTc *= lamTc; lamTc *= lamTc; lamTc *= lamTc;
  lamTc *= lamTc; lamTc *= lamTc; lamTc *= lamTc;
  float run = 0.f;
  carry[(((size_t)(b * CCH + 0)) * KLAM + k) * DDIM + d] = 0.f;
  for (int c = 1; c < CCH; ++c) {
    run = fmaf(lamTc, run, mfin[(((size_t)(b * CCH + c - 1)) * KLAM + k) * DDIM + d]);
    carry[(((size_t)(b * CCH + c)) * KLAM + k) * DDIM + d] = run;
  }
}

// ---------------- carry correction + LayerNorm (block per (b,t)) ----------------
__global__ __launch_bounds__(256) void ln_fuse(const ushort_t* __restrict__ hpart,
                                               const float* __restrict__ carry,
                                               const float* __restrict__ lam_logit,
                                               const float* __restrict__ eta,
                                               const float* __restrict__ gamma,
                                               const float* __restrict__ beta,
                                               float* __restrict__ out) {
  int bt = blockIdx.x;            // b*TDIM + t
  int t = bt & (TDIM - 1);
  int b = bt >> 11;
  int c = t >> 6;                 // chunk
  int dt = (t & (TC - 1)) + 1;

  float sc[KLAM];
#pragma unroll
  for (int k = 0; k < KLAM; ++k) {
    float lam = 1.f / (1.f + __expf(-lam_logit[k]));
    sc[k] = eta[k] * powf(lam, (float)dt);
  }

  int d0 = threadIdx.x * 8;
  size_t rowoff = (size_t)bt * DDIM;

  float h[8];
  {
    uint4 hv = *(const uint4*)&hpart[rowoff + d0];
    h[0] = bf2f(hv.x & 0xffffu); h[1] = bf2f(hv.x >> 16);
    h[2] = bf2f(hv.y & 0xffffu); h[3] = bf2f(hv.y >> 16);
    h[4] = bf2f(hv.z & 0xffffu); h[5] = bf2f(hv.z >> 16);
    h[6] = bf2f(hv.w & 0xffffu); h[7] = bf2f(hv.w >> 16);
  }
  size_t cb = ((size_t)(b * CCH + c)) * KLAM * DDIM + d0;
#pragma unroll
  for (int k = 0; k < KLAM; ++k) {
    float4 c0 = *(const float4*)&carry[cb + (size_t)k * DDIM];
    float4 c1 = *(const float4*)&carry[cb + (size_t)k * DDIM + 4];
    h[0] = fmaf(sc[k], c0.x, h[0]);
    h[1] = fmaf(sc[k], c0.y, h[1]);
    h[2] = fmaf(sc[k], c0.z, h[2]);
    h[3] = fmaf(sc[k], c0.w, h[3]);
    h[4] = fmaf(sc[k], c1.x, h[4]);
    h[5] = fmaf(sc[k], c1.y, h[5]);
    h[6] = fmaf(sc[k], c1.z, h[6]);
    h[7] = fmaf(sc[k], c1.w, h[7]);
  }

  float s = 0.f, ss = 0.f;
#pragma unroll
  for (int j = 0; j < 8; ++j) { s += h[j]; ss += h[j] * h[j]; }
#pragma unroll
  for (int off = 32; off > 0; off >>= 1) {
    s  += __shfl_xor(s, off, 64);
    ss += __shfl_xor(ss, off, 64);
  }
  __shared__ float red[8];
  int wv = threadIdx.x >> 6;
  if ((threadIdx.x & 63) == 0) { red[wv] = s; red[4 + wv] = ss; }
  __syncthreads();
  float st  = red[0] + red[1] + red[2] + red[3];
  float sst = red[4] + red[5] + red[6] + red[7];

  const float invD = 1.f / (float)DDIM;
  float mu = st * invD;
  float var = sst * invD - mu * mu;
  float inv = rsqrtf(var + 1e-5f);

  float4 g0 = *(const float4*)&gamma[d0];
  float4 g1 = *(const float4*)&gamma[d0 + 4];
  float4 b0 = *(const float4*)&beta[d0];
  float4 b1 = *(const float4*)&beta[d0 + 4];
  float4 o0, o1;
  o0.x = g0.x * (h[0] - mu) * inv + b0.x;
  o0.y = g0.y * (h[1] - mu) * inv + b0.y;
  o0.z = g0.z * (h[2] - mu) * inv + b0.z;
  o0.w = g0.w * (h[3] - mu) * inv + b0.w;
  o1.x = g1.x * (h[4] - mu) * inv + b1.x;
  o1.y = g1.y * (h[5] - mu) * inv + b1.y;
  o1.z = g1.z * (h[6] - mu) * inv + b1.z;
  o1.w = g1.w * (h[7] - mu) * inv + b1.w;
  *(float4*)&out[rowoff + d0] = o0;
  *(float4*)&out[rowoff + d0 + 4] = o1;
}

extern "C" void kernel_launch(void* const* d_in, const int* in_sizes, int n_in,
                              void* d_out, int out_size, void* d_ws, size_t ws_size,
                              hipStream_t stream) {
  const float* x         = (const float*)d_in[0];
  const float* W         = (const float*)d_in[1];
  const float* lam_logit = (const float*)d_in[2];
  const float* eta       = (const float*)d_in[3];
  const float* gamma     = (const float*)d_in[4];
  const float* beta      = (const float*)d_in[5];
  float* out = (float*)d_out;

  char* ws = (char*)d_ws;
  // layout: [xb 32MB][Wb 8MB][zb 32MB bf16]; mfin/carry (4MB each) overlay xb after GEMM
  ushort_t* xb = (ushort_t*)ws;
  ushort_t* Wb = (ushort_t*)(ws + (size_t)33554432);
  ushort_t* zb = (ushort_t*)(ws + (size_t)33554432 + 8388608);
  float*    mfin  = (float*)ws;                       // reuses xb region (dead after GEMM)
  float*    carry = (float*)(ws + (size_t)4194304);   // still inside xb region

  const int nX8 = (BDIM * TDIM * DDIM) / 8;  // 2097152
  const int nW8 = (DDIM * DDIM) / 8;         // 524288
  cvt_bf16<<<nX8 / 256, 256, 0, stream>>>(x, (uint4*)xb, nX8);
  cvt_bf16<<<nW8 / 256, 256, 0, stream>>>(W, (uint4*)Wb, nW8);

  gemm256<<<256, 512, 0, stream>>>(xb, Wb, zb);

  scan_local<<<BDIM * CCH * 4, 256, 0, stream>>>(zb, mfin, lam_logit, eta);
  scan_carry<<<(BDIM * KLAM * DDIM) / 256, 256, 0, stream>>>(mfin, carry, lam_logit);
  ln_fuse<<<BDIM * TDIM, 256, 0, stream>>>(zb, carry, lam_logit, eta, gamma, beta, out);
}